// Round 1
// baseline (191.952 us; speedup 1.0000x reference)
//
#include <hip/hip_runtime.h>

#define P_N 40000
#define M_N 100
#define NB1 512   // blocks for moment kernel

// ---------------- Kernel 1: per-pillar means + global feature moments ----------------

__device__ __forceinline__ void acc_point(float (&a1)[9], float (&a2)[45], const float f[9]) {
  #pragma unroll
  for (int c = 0; c < 9; ++c) a1[c] += f[c];
  int k = 0;
  #pragma unroll
  for (int c = 0; c < 9; ++c) {
    #pragma unroll
    for (int c2 = c; c2 < 9; ++c2) {
      a2[k] = fmaf(f[c], f[c2], a2[k]);
      ++k;
    }
  }
}

__global__ __launch_bounds__(256) void k_moments(
    const float* __restrict__ px, const float* __restrict__ py,
    const float* __restrict__ pz, const float* __restrict__ pi,
    const int* __restrict__ npp, const int* __restrict__ coors,
    float* __restrict__ partials, float* __restrict__ means)
{
  const int lane = threadIdx.x & 63;
  const int wid  = threadIdx.x >> 6;
  const int wpb  = blockDim.x >> 6;        // 4 waves per block
  const int nw   = wpb * gridDim.x;

  float a1[9]; float a2[45];
  #pragma unroll
  for (int i = 0; i < 9; ++i) a1[i] = 0.f;
  #pragma unroll
  for (int i = 0; i < 45; ++i) a2[i] = 0.f;

  for (int p = blockIdx.x * wpb + wid; p < P_N; p += nw) {
    const float* xr = px + (size_t)p * M_N;
    const float* yr = py + (size_t)p * M_N;
    const float* zr = pz + (size_t)p * M_N;
    const float* ir = pi + (size_t)p * M_N;

    float x0 = xr[lane], y0 = yr[lane], z0 = zr[lane], i0 = ir[lane];
    const bool h2 = (lane + 64) < M_N;      // lanes 0..35 carry a second point
    float x1 = h2 ? xr[lane + 64] : 0.f;
    float y1 = h2 ? yr[lane + 64] : 0.f;
    float z1 = h2 ? zr[lane + 64] : 0.f;
    float i1 = h2 ? ir[lane + 64] : 0.f;

    // full (unmasked) sums for the means
    float sx = x0 + x1, sy = y0 + y1, sz = z0 + z1;
    #pragma unroll
    for (int off = 32; off; off >>= 1) {
      sx += __shfl_xor(sx, off);
      sy += __shfl_xor(sy, off);
      sz += __shfl_xor(sz, off);
    }
    const int n  = npp[p];
    const int nc = n < 1 ? 1 : n;
    const float inv = 1.f / (float)nc;
    const float mx = sx * inv, my = sy * inv, mz = sz * inv;

    const int c2 = coors[p * 4 + 2], c3 = coors[p * 4 + 3];
    const float xb = fmaf((float)c3, 0.16f, 0.08f);            // X0 = 0
    const float yb = fmaf((float)c2, 0.16f, 0.08f - 39.68f);   // Y0 = -39.68

    if (lane == 0) {
      means[p * 4 + 0] = mx;
      means[p * 4 + 1] = my;
      means[p * 4 + 2] = mz;
    }

    if (lane < n) {
      float f[9] = {x0, y0, z0, i0, x0 - mx, y0 - my, z0 - mz, xb, yb};
      acc_point(a1, a2, f);
    }
    if (lane + 64 < n) {
      float f[9] = {x1, y1, z1, i1, x1 - mx, y1 - my, z1 - mz, xb, yb};
      acc_point(a1, a2, f);
    }
  }

  // wave reduce all 54 accumulators
  #pragma unroll
  for (int off = 32; off; off >>= 1) {
    #pragma unroll
    for (int i = 0; i < 9; ++i)  a1[i] += __shfl_xor(a1[i], off);
    #pragma unroll
    for (int i = 0; i < 45; ++i) a2[i] += __shfl_xor(a2[i], off);
  }

  __shared__ float red[4][54];
  if (lane == 0) {
    #pragma unroll
    for (int i = 0; i < 9; ++i)  red[wid][i]     = a1[i];
    #pragma unroll
    for (int i = 0; i < 45; ++i) red[wid][9 + i] = a2[i];
  }
  __syncthreads();
  if (threadIdx.x < 54) {
    const int t = threadIdx.x;
    partials[blockIdx.x * 54 + t] = red[0][t] + red[1][t] + red[2][t] + red[3][t];
  }
}

// ---------------- Kernel 2: reduce partials -> per-channel BN scale/shift ----------------

__global__ __launch_bounds__(256) void k_stats(
    const float* __restrict__ partials, const float* __restrict__ W,
    const float* __restrict__ gamma, const float* __restrict__ beta,
    float* __restrict__ scale, float* __restrict__ shift)
{
  __shared__ float red[216];
  __shared__ float mom[54];
  const int tid = threadIdx.x;

  if (tid < 216) {
    const int c = tid % 54, r = tid / 54;
    float s = 0.f;
    for (int b = r; b < NB1; b += 4) s += partials[b * 54 + c];
    red[tid] = s;
  }
  __syncthreads();
  if (tid < 54) mom[tid] = red[tid] + red[tid + 54] + red[tid + 108] + red[tid + 162];
  __syncthreads();

  if (tid < 64) {
    float w[9];
    #pragma unroll
    for (int c = 0; c < 9; ++c) w[c] = W[c * 64 + tid];
    const float invN = 1.f / ((float)P_N * (float)M_N);
    float mu = 0.f;
    #pragma unroll
    for (int c = 0; c < 9; ++c) mu += mom[c] * w[c];
    mu *= invN;
    float e2 = 0.f;
    int k = 0;
    #pragma unroll
    for (int c = 0; c < 9; ++c) {
      #pragma unroll
      for (int c2 = c; c2 < 9; ++c2) {
        const float t = w[c] * w[c2] * mom[9 + k];
        e2 += (c == c2) ? t : 2.f * t;
        ++k;
      }
    }
    e2 *= invN;
    float var = e2 - mu * mu;
    var = var < 0.f ? 0.f : var;
    const float sc = gamma[tid] * rsqrtf(var + 1e-5f);
    const float sh = fmaf(-mu, sc, beta[tid]);
    scale[tid] = sc;
    shift[tid] = sh;
  }
}

// ---------------- Kernel 3: fused linear+BN+ReLU+max, lane = channel ----------------

__global__ __launch_bounds__(256) void k_out(
    const float* __restrict__ px, const float* __restrict__ py,
    const float* __restrict__ pz, const float* __restrict__ pi,
    const int* __restrict__ npp, const int* __restrict__ coors,
    const float* __restrict__ W, const float* __restrict__ scale,
    const float* __restrict__ shift, const float* __restrict__ means,
    float* __restrict__ out)
{
  const int lane = threadIdx.x & 63;
  const int wid  = threadIdx.x >> 6;
  const int wpb  = blockDim.x >> 6;
  const int nw   = wpb * gridDim.x;
  const int d    = lane;

  const float sc = scale[d], sh = shift[d];
  float w[9];
  #pragma unroll
  for (int c = 0; c < 9; ++c) w[c] = W[c * 64 + d];
  // combined weights: x_lin = x*(w0+w4) + y*(w1+w5) + z*(w2+w6) + i*w3 + E(pillar)
  const float sA = sc * (w[0] + w[4]);
  const float sB = sc * (w[1] + w[5]);
  const float sC = sc * (w[2] + w[6]);
  const float sD = sc * w[3];
  const float s4 = sc * w[4], s5 = sc * w[5], s6 = sc * w[6];
  const float s7 = sc * w[7], s8 = sc * w[8];

  for (int p0 = blockIdx.x * wpb + wid; p0 < P_N; p0 += nw) {
    const int p = __builtin_amdgcn_readfirstlane(p0);
    const float* xr = px + (size_t)p * M_N;
    const float* yr = py + (size_t)p * M_N;
    const float* zr = pz + (size_t)p * M_N;
    const float* ir = pi + (size_t)p * M_N;

    const int n  = npp[p];
    const int c2 = coors[p * 4 + 2], c3 = coors[p * 4 + 3];
    const float mx = means[p * 4 + 0], my = means[p * 4 + 1], mz = means[p * 4 + 2];
    const float xb = fmaf((float)c3, 0.16f, 0.08f);
    const float yb = fmaf((float)c2, 0.16f, 0.08f - 39.68f);

    float sE = sh;
    sE = fmaf(-mx, s4, sE);
    sE = fmaf(-my, s5, sE);
    sE = fmaf(-mz, s6, sE);
    sE = fmaf( xb, s7, sE);
    sE = fmaf( yb, s8, sE);

    int v = n < M_N ? n : M_N;          // number of valid (unmasked) points
    // masked points contribute h = shift; there is always one when v < M
    float acc = (v < M_N) ? sh : -3.0e38f;

    for (int mb = 0; mb < v; mb += 8) {
      float xs[8], ys[8], zs[8], qs[8];
      #pragma unroll
      for (int j = 0; j < 8; ++j) {
        int mm = mb + j;
        mm = mm < M_N ? mm : (M_N - 1);  // clamp tail loads in-bounds
        xs[j] = xr[mm]; ys[j] = yr[mm]; zs[j] = zr[mm]; qs[j] = ir[mm];
      }
      #pragma unroll
      for (int j = 0; j < 8; ++j) {
        float t = fmaf(xs[j], sA, sE);
        t = fmaf(ys[j], sB, t);
        t = fmaf(zs[j], sC, t);
        t = fmaf(qs[j], sD, t);
        const bool ok = (mb + j) < v;
        const float cand = fmaxf(acc, t);
        acc = ok ? cand : acc;
      }
    }
    // max(relu(h)) == relu(max(h))
    out[(size_t)p * 64 + d] = fmaxf(acc, 0.f);
  }
}

// ---------------- launch ----------------

extern "C" void kernel_launch(void* const* d_in, const int* in_sizes, int n_in,
                              void* d_out, int out_size, void* d_ws, size_t ws_size,
                              hipStream_t stream) {
  const float* px    = (const float*)d_in[0];
  const float* py    = (const float*)d_in[1];
  const float* pz    = (const float*)d_in[2];
  const float* pi    = (const float*)d_in[3];
  const int*   npp   = (const int*)d_in[4];
  const int*   coors = (const int*)d_in[5];
  const float* W     = (const float*)d_in[6];
  const float* gamma = (const float*)d_in[7];
  const float* beta  = (const float*)d_in[8];
  float* out = (float*)d_out;

  float* wsf      = (float*)d_ws;
  float* partials = wsf;                    // NB1*54 = 27648 floats
  float* scale    = wsf + 27648;            // 64
  float* shift    = wsf + 27712;            // 64
  float* means    = wsf + 28672;            // 4*P_N floats (x,y,z,pad)

  k_moments<<<NB1, 256, 0, stream>>>(px, py, pz, pi, npp, coors, partials, means);
  k_stats<<<1, 256, 0, stream>>>(partials, W, gamma, beta, scale, shift);
  k_out<<<2500, 256, 0, stream>>>(px, py, pz, pi, npp, coors, W, scale, shift, means, out);
}